// Round 2
// baseline (504.853 us; speedup 1.0000x reference)
//
#include <hip/hip_runtime.h>

#define NROWS 392      // B*N = 2*196
#define NSAMP 500
#define DDIM  256
#define KSEL  32
#define SIGMA 0.05f

__device__ __forceinline__ int mbcnt64(unsigned long long m) {
    int lo = __builtin_amdgcn_mbcnt_lo((unsigned)m, 0u);
    return __builtin_amdgcn_mbcnt_hi((unsigned)(m >> 32), lo);
}

// One wave (64 lanes) per (row, sample). Lane holds 4 contiguous values:
// d = 4*lane + j  -> single dwordx4 load per lane for noise and for x.
__global__ __launch_bounds__(256) void ptopk_count_kernel(
    const float* __restrict__ x,      // (392, 256)
    const float* __restrict__ noise,  // (392, 500, 256)
    unsigned int* __restrict__ counts // (392, 32, 256), pre-zeroed
) {
    const int gtid = blockIdx.x * blockDim.x + threadIdx.x;
    const int wave = gtid >> 6;          // global sample id; exact grid, no bounds check
    const int lane = gtid & 63;
    const int row  = wave / NSAMP;

    const float4 xv = *(const float4*)(x + row * DDIM + 4 * lane);
    const float4 nv = *(const float4*)(noise + (size_t)wave * DDIM + 4 * lane);

    unsigned int u[4];
    {
        float v[4] = { __builtin_fmaf(SIGMA, nv.x, xv.x),
                       __builtin_fmaf(SIGMA, nv.y, xv.y),
                       __builtin_fmaf(SIGMA, nv.z, xv.z),
                       __builtin_fmaf(SIGMA, nv.w, xv.w) };
        #pragma unroll
        for (int j = 0; j < 4; ++j) {
            unsigned int b = __float_as_uint(v[j]);
            // order-preserving uint transform
            u[j] = b ^ ((unsigned)(((int)b) >> 31) | 0x80000000u);
        }
    }

    // Bitwise binary search (radix select) for the 32nd-largest value.
    unsigned int t = 0u;
    for (int bit = 31; bit >= 0; --bit) {
        const unsigned int cand = t | (1u << bit);
        int cnt = __popcll(__ballot(u[0] >= cand))
                + __popcll(__ballot(u[1] >= cand))
                + __popcll(__ballot(u[2] >= cand))
                + __popcll(__ballot(u[3] >= cand));
        if (cnt >= KSEL) {
            t = cand;
            if (cnt == KSEL) break;   // exact separation (wave-uniform branch)
        }
    }

    // Selection masks; rank = position in ascending-d order (matches jnp.sort(idx)).
    unsigned long long m[4];
    #pragma unroll
    for (int j = 0; j < 4; ++j) m[j] = __ballot(u[j] >= t);

    // bits of each m[j] in lanes strictly below this lane
    const int below = mbcnt64(m[0]) + mbcnt64(m[1]) + mbcnt64(m[2]) + mbcnt64(m[3]);

    unsigned int* crow = counts + (size_t)row * (KSEL * DDIM);
    int own = 0;  // selected elements in this lane with smaller j
    #pragma unroll
    for (int j = 0; j < 4; ++j) {
        if (u[j] >= t) {
            const int r = below + own;
            if (r < KSEL) {          // tie-at-threshold guard (no OOB writes)
                const int d = 4 * lane + j;
                atomicAdd(&crow[r * DDIM + d], 1u);
            }
            ++own;
        }
    }
}

// In-place uint counts -> float counts/NSAMP (writes every element of d_out).
__global__ __launch_bounds__(256) void ptopk_finalize_kernel(unsigned int* data, int n, float inv) {
    const int i = blockIdx.x * blockDim.x + threadIdx.x;
    if (i < n) {
        const unsigned int c = data[i];
        ((float*)data)[i] = (float)c * inv;
    }
}

extern "C" void kernel_launch(void* const* d_in, const int* in_sizes, int n_in,
                              void* d_out, int out_size, void* d_ws, size_t ws_size,
                              hipStream_t stream) {
    const float* x     = (const float*)d_in[0];
    const float* noise = (const float*)d_in[1];
    // k (d_in[2]) is fixed at 32 by setup_inputs; layout hardcoded.

    unsigned int* counts = (unsigned int*)d_out;
    const int n_out = NROWS * KSEL * DDIM;   // == out_size

    hipMemsetAsync(d_out, 0, (size_t)n_out * sizeof(unsigned int), stream);

    const int nwaves = NROWS * NSAMP;                 // 196,000 samples
    const int blocks = (nwaves * 64) / 256;           // exact: 49,000 blocks of 4 waves
    ptopk_count_kernel<<<blocks, 256, 0, stream>>>(x, noise, counts);

    ptopk_finalize_kernel<<<(n_out + 255) / 256, 256, 0, stream>>>(counts, n_out, 1.0f / NSAMP);
}

// Round 4
// 313.339 us; speedup vs baseline: 1.6112x; 1.6112x over previous
//
#include <hip/hip_runtime.h>

#define NROWS 392      // B*N = 2*196
#define NSAMP 500
#define DDIM  256
#define KSEL  32
#define SIGMA 0.05f
#define PAIRS (KSEL * DDIM / 2)   // 4096 packed u16-pair counters per partial

__device__ __forceinline__ int mbcnt64(unsigned long long m) {
    int lo = __builtin_amdgcn_mbcnt_lo((unsigned)m, 0u);
    return __builtin_amdgcn_mbcnt_hi((unsigned)(m >> 32), lo);
}

// One block per (row, sample-chunk). 512 threads = 8 waves; wave w handles
// samples sbeg+w, sbeg+w+8, ... Counts accumulate in LDS (u16 pairs packed in
// u32: d and d+1 share a word; per-half max <= NSAMP < 65536, no carry).
__global__ __launch_bounds__(512) void ptopk_count_kernel(
    const float* __restrict__ x,        // (392, 256)
    const float* __restrict__ noise,    // (392, 500, 256)
    unsigned int* __restrict__ partial, // (NROWS*split, PAIRS)
    int split)
{
    __shared__ unsigned int cnt[PAIRS]; // 16 KB
    const int tid  = threadIdx.x;
    const int lane = tid & 63;
    const int wid  = tid >> 6;          // 0..7
    const int blk  = blockIdx.x;
    const int row  = blk / split;
    const int chunk = NSAMP / split;
    const int sbeg = (blk % split) * chunk;
    const int send = sbeg + chunk;

    for (int i = tid; i < PAIRS; i += 512) cnt[i] = 0u;

    // x is row-invariant: load once per wave. Lane owns d = 4*lane..4*lane+3.
    const float4 xv = *(const float4*)(x + row * DDIM + 4 * lane);
    const float* nrow = noise + (size_t)row * NSAMP * DDIM;
    __syncthreads();

    int s = sbeg + wid;
    float4 nv;
    if (s < send) nv = *(const float4*)(nrow + (size_t)s * DDIM + 4 * lane);

    for (; s < send; s += 8) {
        // prefetch next sample's noise (double-buffer) to hide HBM latency
        float4 nvn = nv;
        const int sn = s + 8;
        if (sn < send) nvn = *(const float4*)(nrow + (size_t)sn * DDIM + 4 * lane);

        unsigned int u[4];
        {
            const float v0 = __builtin_fmaf(SIGMA, nv.x, xv.x);
            const float v1 = __builtin_fmaf(SIGMA, nv.y, xv.y);
            const float v2 = __builtin_fmaf(SIGMA, nv.z, xv.z);
            const float v3 = __builtin_fmaf(SIGMA, nv.w, xv.w);
            const float vv[4] = { v0, v1, v2, v3 };
            #pragma unroll
            for (int j = 0; j < 4; ++j) {
                unsigned int b = __float_as_uint(vv[j]);
                u[j] = b ^ ((unsigned)(((int)b) >> 31) | 0x80000000u); // order-preserving
            }
        }

        // Radix-select the 32nd-largest (as ordered uint).
        unsigned int t = 0u;
        for (int bit = 31; bit >= 0; --bit) {
            const unsigned int cand = t | (1u << bit);
            int c = __popcll(__ballot(u[0] >= cand))
                  + __popcll(__ballot(u[1] >= cand))
                  + __popcll(__ballot(u[2] >= cand))
                  + __popcll(__ballot(u[3] >= cand));
            if (c >= KSEL) {
                t = cand;
                if (c == KSEL) break;   // wave-uniform early exit
            }
        }

        // rank = position within selected set in ascending d (== jnp.sort(idx))
        unsigned long long m[4];
        #pragma unroll
        for (int j = 0; j < 4; ++j) m[j] = __ballot(u[j] >= t);
        const int below = mbcnt64(m[0]) + mbcnt64(m[1]) + mbcnt64(m[2]) + mbcnt64(m[3]);

        int own = 0;
        #pragma unroll
        for (int j = 0; j < 4; ++j) {
            if (u[j] >= t) {
                const int r = below + own;
                if (r < KSEL) { // tie guard: no OOB
                    // d = 4*lane+j  ->  pair word r*128 + 2*lane + (j>>1), half j&1
                    atomicAdd(&cnt[r * 128 + 2 * lane + (j >> 1)],
                              (j & 1) ? 0x10000u : 1u);
                }
                ++own;
            }
        }
        nv = nvn;
    }

    __syncthreads();
    unsigned int* dst = partial + (size_t)blk * PAIRS;
    for (int i = tid; i < PAIRS; i += 512) dst[i] = cnt[i]; // coalesced plain stores
}

// Sum `split` partials, unpack u16 halves, scale, write float2.
__global__ __launch_bounds__(256) void ptopk_reduce_kernel(
    const unsigned int* __restrict__ partial,
    float2* __restrict__ out, int split, float inv)
{
    const int g   = blockIdx.x * 256 + threadIdx.x;   // pair id, exact grid
    const int row = g / PAIRS;
    const int p   = g - row * PAIRS;
    const unsigned int* src = partial + (size_t)(row * split) * PAIRS + p;
    unsigned int lo = 0, hi = 0;
    for (int s = 0; s < split; ++s) {
        const unsigned int w = src[(size_t)s * PAIRS];
        lo += w & 0xFFFFu;
        hi += w >> 16;
    }
    out[g] = make_float2((float)lo * inv, (float)hi * inv);
}

extern "C" void kernel_launch(void* const* d_in, const int* in_sizes, int n_in,
                              void* d_out, int out_size, void* d_ws, size_t ws_size,
                              hipStream_t stream) {
    const float* x     = (const float*)d_in[0];
    const float* noise = (const float*)d_in[1];
    // k (d_in[2]) fixed at 32 by setup_inputs; layout hardcoded.

    // choose split by available workspace (deterministic every call)
    int split = 1;
    if (ws_size >= (size_t)NROWS * 4 * PAIRS * sizeof(unsigned int)) split = 4;
    else if (ws_size >= (size_t)NROWS * 2 * PAIRS * sizeof(unsigned int)) split = 2;

    unsigned int* partial = (unsigned int*)d_ws;

    ptopk_count_kernel<<<NROWS * split, 512, 0, stream>>>(x, noise, partial, split);

    const int npairs = NROWS * PAIRS;                 // 1,605,632 = 6272*256 exact
    ptopk_reduce_kernel<<<npairs / 256, 256, 0, stream>>>(
        partial, (float2*)d_out, split, 1.0f / NSAMP);
}